// Round 10
// baseline (255.307 us; speedup 1.0000x reference)
//
#include <hip/hip_runtime.h>

#define FUZZ 2187
#define NFEAT 7
#define MID 512
#define NCLS 10
#define BATCH 4096
#define SSTR 2192   // padded row stride for S (21 rows)

constexpr int pw3(int e) { int r = 1; while (e--) r *= 3; return r; }

// ---------------------------------------------------------------------------
// Kernel 1: grid (35, 24) x 512 threads.
//  y in [0,3):  K-part. kb = y*35+bx < 80: c = kb>>3, i-tile = kb&7.
//               K[c][i] = sum_n W3[c,n]*W2[n,i] — 8 waves split n (273/274
//               each), 13-deep W2 load bursts, LDS reduce, plain store.
//               Dispatched FIRST (y ascending) so these longer blocks overlap
//               the S-part bulk instead of straggling at the end.
//  y in [3,24): S-part (g = y-3 = 3j+m), byte-identical logic to round 9:
//               atomic-free, 8 waves split 729 k's, 13-deep bursts.
//               Block (g==0, bx==0) zeroes T/H/v/w (288 floats).
// K is plain-stored (single writer) -> no zero race in-dispatch.
// ---------------------------------------------------------------------------
template<int J>
__device__ __forceinline__ float group_range(const float* __restrict__ wei,
                                             int m, int n, int e0, int cnt) {
    constexpr int PL = pw3(6 - J);
    float acc = 0.f;
    int e = e0;
    int eend = e0 + cnt;
    while (e + 13 <= eend) {
        float v[13];
#pragma unroll
        for (int u = 0; u < 13; ++u) {
            int ee = e + u;
            int hi = ee / PL;               // compile-time PL -> magic mul
            int lo = ee - hi * PL;
            int k  = (hi * 3 + m) * PL + lo;
            v[u] = wei[((size_t)k * 7 + J) * FUZZ + n];
        }
#pragma unroll
        for (int u = 0; u < 13; ++u) acc += v[u];
        e += 13;
    }
    while (e < eend) {
        int hi = e / PL;
        int lo = e - hi * PL;
        int k  = (hi * 3 + m) * PL + lo;
        acc += wei[((size_t)k * 7 + J) * FUZZ + n];
        ++e;
    }
    return acc;
}

__global__ __launch_bounds__(512) void k_reduce_wei(const float* __restrict__ wei,
                                                    const float* __restrict__ W2,
                                                    const float* __restrict__ W3,
                                                    float* __restrict__ S,
                                                    float* __restrict__ K,
                                                    float* __restrict__ THvw) {
    int tid = threadIdx.x;
    int w = tid >> 6, lane = tid & 63;
    __shared__ float red[8][64];

    if (blockIdx.y < 3) {                   // ---- K-part ----
        int kb = blockIdx.y * 35 + blockIdx.x;
        if (kb >= 80) return;
        int c = kb >> 3;
        int i = (kb & 7) * 64 + lane;
        int start = w * 273 + (w < 3 ? w : 3);
        int cnt = 273 + (w < 3 ? 1 : 0);    // 2187 = 3*274 + 5*273
        const float* w3row = W3 + (size_t)c * FUZZ;
        const float* w2col = W2 + i;
        float acc = 0.f;
        int n = start, nend = start + cnt;
        while (n + 13 <= nend) {
            float vv[13];
#pragma unroll
            for (int u = 0; u < 13; ++u)
                vv[u] = w2col[(size_t)(n + u) * MID];
#pragma unroll
            for (int u = 0; u < 13; ++u) acc += vv[u] * w3row[n + u];
            n += 13;
        }
        while (n < nend) { acc += w2col[(size_t)n * MID] * w3row[n]; ++n; }
        red[w][lane] = acc;
        __syncthreads();
        if (w == 0) {
            float s = 0.f;
#pragma unroll
            for (int ww = 0; ww < 8; ++ww) s += red[ww][lane];
            K[(size_t)c * MID + i] = s;
        }
        return;
    }

    // ---- S-part ----
    int g = blockIdx.y - 3;                 // 0..20: g = 3*j + m
    if (g == 0 && blockIdx.x == 0) {        // zero T(32)+H(224)+v(16)+w(16)
        if (tid < 288) THvw[tid] = 0.f;
    }
    int n = blockIdx.x * 64 + lane;
    int j = g / 3, m = g % 3;
    float acc = 0.f;
    int e0 = w * 91;
    int cnt = (w == 7) ? 92 : 91;           // 729 = 7*91 + 92
    if (n < FUZZ) {
        switch (j) {
            case 0: acc = group_range<0>(wei, m, n, e0, cnt); break;
            case 1: acc = group_range<1>(wei, m, n, e0, cnt); break;
            case 2: acc = group_range<2>(wei, m, n, e0, cnt); break;
            case 3: acc = group_range<3>(wei, m, n, e0, cnt); break;
            case 4: acc = group_range<4>(wei, m, n, e0, cnt); break;
            case 5: acc = group_range<5>(wei, m, n, e0, cnt); break;
            default: acc = group_range<6>(wei, m, n, e0, cnt); break;
        }
    }
    red[w][lane] = acc;
    __syncthreads();
    if (w == 0 && n < FUZZ) {
        float s = 0.f;
#pragma unroll
        for (int ww = 0; ww < 8; ++ww) s += red[ww][lane];
        S[g * SSTR + n] = s;
    }
}

__device__ __forceinline__ float wave_sum(float v) {
#pragma unroll
    for (int off = 32; off > 0; off >>= 1) v += __shfl_down(v, off, 64);
    return v;
}

// ---------------------------------------------------------------------------
// Kernel 2: W3eff[c][n] = W3[c,n] + sum_i K[c,i]*W1[i,n]   (10 x 2187)
//           v[c] = sum_n W3eff[c,n]        (atomicAdd over 35 n-tiles)
//           w[c] = sum_i b1[i]*K[c,i] + sum_n b2[n]*W3[c,n] + b3[c]
// Grid (35, 10) x 512: block = (n-tile of 64, c); 8 waves split i (64 each);
// LDS reduce; wave 0 stores W3eff + v-partial, wave 1 does b2*W3 partial,
// wave 2 (bx==0) does the b1*K + b3 term. Replaces the old 512-block SW1
// GEMM: H = S*W3^T + (S*W1^T)*K^T == S*W3eff^T.
// ---------------------------------------------------------------------------
__global__ __launch_bounds__(512) void k_w3eff(const float* __restrict__ K,
                                               const float* __restrict__ W1,
                                               const float* __restrict__ W3,
                                               const float* __restrict__ b1,
                                               const float* __restrict__ b2,
                                               const float* __restrict__ b3,
                                               float* __restrict__ W3E,
                                               float* __restrict__ v,
                                               float* __restrict__ w) {
    int c = blockIdx.y;
    int bx = blockIdx.x;
    int tid = threadIdx.x;
    int wv = tid >> 6, lane = tid & 63;
    int n = bx * 64 + lane;
    bool nok = (n < FUZZ);
    const float* krow = K + (size_t)c * MID;
    float acc = 0.f;
    if (nok) {
        int i0 = wv * 64;
        const float* w1p = W1 + (size_t)i0 * FUZZ + n;
#pragma unroll 8
        for (int u = 0; u < 64; ++u)
            acc += krow[i0 + u] * w1p[(size_t)u * FUZZ];
    }
    __shared__ float red[8][64];
    red[wv][lane] = acc;
    __syncthreads();
    if (wv == 0) {
        float s = 0.f;
#pragma unroll
        for (int ww = 0; ww < 8; ++ww) s += red[ww][lane];
        float w3e = nok ? (s + W3[(size_t)c * FUZZ + n]) : 0.f;
        if (nok) W3E[(size_t)c * FUZZ + n] = w3e;
        float vs = wave_sum(w3e);
        if (lane == 0) atomicAdd(&v[c], vs);
    } else if (wv == 1) {
        float ws = nok ? b2[n] * W3[(size_t)c * FUZZ + n] : 0.f;
        ws = wave_sum(ws);
        if (lane == 0) atomicAdd(&w[c], ws);
    } else if (wv == 2 && bx == 0) {
        float bs = 0.f;
        for (int i = lane; i < MID; i += 64) bs += b1[i] * krow[i];
        bs = wave_sum(bs);
        if (lane == 0) atomicAdd(&w[c], bs + b3[c]);
    }
}

// ---------------------------------------------------------------------------
// Kernel 3: H[t][c] = sum_n S[t,n]*W3eff[c,n]   (atomicAdd over 9 n-chunks)
//           T[t] = sum_n S[t,n]                 (blockIdx.x == 10)
// Grid (11, 9) x 64. H/T zeroed by k1.
// ---------------------------------------------------------------------------
__global__ __launch_bounds__(64) void k_h(const float* __restrict__ S,
                                          const float* __restrict__ W3E,
                                          float* __restrict__ H,
                                          float* __restrict__ T) {
    int c = blockIdx.x;
    int chunk = blockIdx.y;
    int lane = threadIdx.x;
    int n0 = chunk * 243;
    float acc[21];
#pragma unroll
    for (int t = 0; t < 21; ++t) acc[t] = 0.f;
    if (c < NCLS) {
        const float* w3row = W3E + (size_t)c * FUZZ;
        for (int n = n0 + lane; n < n0 + 243; n += 64) {
            float w3 = w3row[n];
#pragma unroll
            for (int t = 0; t < 21; ++t)
                acc[t] += S[t * SSTR + n] * w3;
        }
#pragma unroll
        for (int t = 0; t < 21; ++t) acc[t] = wave_sum(acc[t]);
        if (lane == 0) {
#pragma unroll
            for (int t = 0; t < 21; ++t) atomicAdd(&H[t * NCLS + c], acc[t]);
        }
    } else {
        for (int n = n0 + lane; n < n0 + 243; n += 64) {
#pragma unroll
            for (int t = 0; t < 21; ++t) acc[t] += S[t * SSTR + n];
        }
#pragma unroll
        for (int t = 0; t < 21; ++t) acc[t] = wave_sum(acc[t]);
        if (lane == 0) {
#pragma unroll
            for (int t = 0; t < 21; ++t) atomicAdd(&T[t], acc[t]);
        }
    }
}

// ---------------------------------------------------------------------------
// Kernel 4: per-batch epilogue. 64 blocks x 64 threads.
// ---------------------------------------------------------------------------
__global__ __launch_bounds__(64) void k_out(const float* __restrict__ x,
                                            const float* __restrict__ cc,
                                            const float* __restrict__ bbv,
                                            const float* __restrict__ bais,
                                            const float* __restrict__ T,
                                            const float* __restrict__ H,
                                            const float* __restrict__ v,
                                            const float* __restrict__ w,
                                            float* __restrict__ out) {
    int b = blockIdx.x * 64 + threadIdx.x;
    if (b >= BATCH) return;
    float xv[NFEAT];
#pragma unroll
    for (int j = 0; j < NFEAT; ++j) xv[j] = x[b * NFEAT + j];
    float u[21];
#pragma unroll
    for (int j = 0; j < NFEAT; ++j) {
#pragma unroll
        for (int m = 0; m < 3; ++m) {
            float d = xv[j] - cc[j * 3 + m];
            float bv = bbv[j * 3 + m];
            u[j * 3 + m] = expf(-(d * d) / (bv * bv));
        }
    }
    float ba = bais[0];
    float r = 2187.0f * ba;
#pragma unroll
    for (int t = 0; t < 21; ++t) r += u[t] * T[t];
    float inv = 1.0f / r;
#pragma unroll
    for (int c = 0; c < NCLS; ++c) {
        float s = 0.f;
#pragma unroll
        for (int t = 0; t < 21; ++t) s += u[t] * H[t * NCLS + c];
        float h = (s + ba * v[c]) * inv + w[c];
        out[b * NCLS + c] = (h >= 0.f) ? h : 0.2f * h;
    }
}

extern "C" void kernel_launch(void* const* d_in, const int* in_sizes, int n_in,
                              void* d_out, int out_size, void* d_ws, size_t ws_size,
                              hipStream_t stream) {
    const float* x    = (const float*)d_in[0];
    const float* c    = (const float*)d_in[1];
    const float* bbv  = (const float*)d_in[2];
    const float* wei  = (const float*)d_in[3];
    const float* bais = (const float*)d_in[4];
    const float* W1   = (const float*)d_in[5];
    const float* b1   = (const float*)d_in[6];
    const float* W2   = (const float*)d_in[7];
    const float* b2   = (const float*)d_in[8];
    const float* W3   = (const float*)d_in[9];
    const float* b3   = (const float*)d_in[10];

    float* ws  = (float*)d_ws;
    float* S   = ws;                         // 21*SSTR (fully overwritten)
    float* T   = S + 21 * SSTR;              // 32   } zeroed by k1 (288)
    float* H   = T + 32;                     // 224  }
    float* v   = H + 224;                    // 16   }
    float* w   = v + 16;                     // 16   }
    float* K   = w + 16;                     // 10*512  (plain-stored)
    float* W3E = K + NCLS * MID;             // 10*2187 (plain-stored)

    k_reduce_wei<<<dim3(35, 24), 512, 0, stream>>>(wei, W2, W3, S, K, T);
    k_w3eff<<<dim3(35, NCLS), 512, 0, stream>>>(K, W1, W3, b1, b2, b3,
                                                W3E, v, w);
    k_h<<<dim3(NCLS + 1, 9), 64, 0, stream>>>(S, W3E, H, T);
    k_out<<<(BATCH + 63) / 64, 64, 0, stream>>>(x, c, bbv, bais, T, H, v, w,
                                                (float*)d_out);
}

// Round 11
// 247.915 us; speedup vs baseline: 1.0298x; 1.0298x over previous
//
#include <hip/hip_runtime.h>

#define FUZZ 2187
#define NFEAT 7
#define MID 512
#define NCLS 10
#define BATCH 4096
#define SSTR 2192   // padded row stride for S (21 rows)

// ---------------------------------------------------------------------------
// Kernel 1: S[jm][n] = sum over k with IDX[k,j]==m of wei[k*7+j, n]
// k = by*9 + kk, by in [0,243): digits d0..d4 block-uniform (5 register
// accumulators, row picked once at the end); kk in [0,9): d5 = kk/3 = burst
// index, d6 = kk%3 compile-time accumulator targets. 11 atomics/thread.
// Grid (9, 243) = 8748 waves = 34/CU.
// MLP: loads are BURST-LOADED 21-at-a-time into named registers, THEN
// accumulated — forces ~21 outstanding loads/wave. Best-measured k1 form
// (session best: 249.2 us total, round 7).
// ---------------------------------------------------------------------------
__global__ __launch_bounds__(256) void k_reduce_wei(const float* __restrict__ wei,
                                                    float* __restrict__ S) {
    int n = blockIdx.x * 256 + threadIdx.x;
    if (n >= FUZZ) return;
    int by = blockIdx.y;            // top 5 base-3 digits of k
    int t = by;
    int d4 = t % 3; t /= 3;
    int d3 = t % 3; t /= 3;
    int d2 = t % 3; t /= 3;
    int d1 = t % 3; t /= 3;
    int d0 = t;                     // by < 243
    float a0 = 0.f, a1 = 0.f, a2 = 0.f, a3 = 0.f, a4 = 0.f;
    float h5[3] = {0.f, 0.f, 0.f};
    float h6[3] = {0.f, 0.f, 0.f};
    const float* base = wei + (size_t)(by * 63) * FUZZ + n;
#pragma unroll
    for (int kb = 0; kb < 3; ++kb) {          // burst = 3 kk = 21 loads
        float v[21];
#pragma unroll
        for (int ki = 0; ki < 3; ++ki)
#pragma unroll
            for (int jj = 0; jj < 7; ++jj)
                v[ki * 7 + jj] =
                    base[(size_t)(((kb * 3 + ki) * 7) + jj) * FUZZ];
        // accumulate after the whole burst is issued
#pragma unroll
        for (int ki = 0; ki < 3; ++ki) {
            a0 += v[ki * 7 + 0];
            a1 += v[ki * 7 + 1];
            a2 += v[ki * 7 + 2];
            a3 += v[ki * 7 + 3];
            a4 += v[ki * 7 + 4];
            h5[kb] += v[ki * 7 + 5];          // d5 = (kb*3+ki)/3 = kb
            h6[ki] += v[ki * 7 + 6];          // d6 = (kb*3+ki)%3 = ki
        }
    }
    atomicAdd(&S[(0  + d0) * SSTR + n], a0);
    atomicAdd(&S[(3  + d1) * SSTR + n], a1);
    atomicAdd(&S[(6  + d2) * SSTR + n], a2);
    atomicAdd(&S[(9  + d3) * SSTR + n], a3);
    atomicAdd(&S[(12 + d4) * SSTR + n], a4);
#pragma unroll
    for (int m = 0; m < 3; ++m) {
        atomicAdd(&S[(15 + m) * SSTR + n], h5[m]);
        atomicAdd(&S[(18 + m) * SSTR + n], h6[m]);
    }
}

__device__ __forceinline__ float wave_sum(float v) {
#pragma unroll
    for (int off = 32; off > 0; off >>= 1) v += __shfl_down(v, off, 64);
    return v;
}

// ---------------------------------------------------------------------------
// Kernel 2 (mixed roles by blockIdx.x):
//   gid in [0,512):      SW1[t][i=gid] = sum_n S[t,n]*W1[i,n]; ws1[i]
//                        (4-wave block, LDS reduce).
//   gid in [512,512+270): K partials. idx=(gid-512): c=idx/27, n-chunk of 81.
//                        Thread tid owns i=tid and i=tid+256; atomicAdd into
//                        K (zeroed by the up-front memset).
// K = W3*W2 (10x512): G*W3^T == SW1*K^T, eliminating the old k_g dispatch.
// ---------------------------------------------------------------------------
__global__ __launch_bounds__(256) void k_sw1(const float* __restrict__ S,
                                             const float* __restrict__ W1,
                                             const float* __restrict__ W2,
                                             const float* __restrict__ W3,
                                             float* __restrict__ SW1,
                                             float* __restrict__ ws1,
                                             float* __restrict__ K) {
    int gid = blockIdx.x;
    int tid = threadIdx.x;
    if (gid >= MID) {
        int idx = gid - MID;        // 0..269
        int c = idx / 27;
        int chunk = idx % 27;
        int n0 = chunk * 81;
        float acc0 = 0.f, acc1 = 0.f;
        const float* w3row = W3 + (size_t)c * FUZZ;
        const float* w2col = W2 + tid;
#pragma unroll 9
        for (int n = n0; n < n0 + 81; ++n) {
            float w3 = w3row[n];
            acc0 += w3 * w2col[(size_t)n * MID];
            acc1 += w3 * w2col[(size_t)n * MID + 256];
        }
        atomicAdd(&K[c * MID + tid],       acc0);
        atomicAdd(&K[c * MID + tid + 256], acc1);
        return;
    }
    int i = gid;
    float acc[21];
    float aw = 0.f;
#pragma unroll
    for (int t = 0; t < 21; ++t) acc[t] = 0.f;
    const float* w1row = W1 + (size_t)i * FUZZ;
    for (int n = tid; n < FUZZ; n += 256) {
        float w1 = w1row[n];
        aw += w1;
#pragma unroll
        for (int t = 0; t < 21; ++t) acc[t] += S[t * SSTR + n] * w1;
    }
#pragma unroll
    for (int t = 0; t < 21; ++t) acc[t] = wave_sum(acc[t]);
    aw = wave_sum(aw);
    __shared__ float red[4][22];
    int w = tid >> 6, lane = tid & 63;
    if (lane == 0) {
#pragma unroll
        for (int t = 0; t < 21; ++t) red[w][t] = acc[t];
        red[w][21] = aw;
    }
    __syncthreads();
    if (tid < 22) {
        float s = red[0][tid] + red[1][tid] + red[2][tid] + red[3][tid];
        if (tid < 21) SW1[tid * MID + i] = s;
        else          ws1[i] = s;
    }
}

// ---------------------------------------------------------------------------
// Kernel 3: H[jm][c] = sum_n S[jm,n]*W3[c,n] + sum_i SW1[jm,i]*K[c,i]
//           v[c] = sum_n W3[c,n] + sum_i ws1[i]*K[c,i]
//           w[c] = sum_i b1[i]*K[c,i] + sum_n b2[n]*W3[c,n] + b3[c]
//           T[jm] = sum_n S[jm,n]               (blockIdx.x == 10)
// Grid (11, 9): n split into 9 chunks of 243; chunks 0..7 additionally own
// i = chunk*64+lane (one i per lane, covers all 512). atomicAdd epilogue
// into T/H/v/w (zeroed by the up-front memset).
// ---------------------------------------------------------------------------
__global__ __launch_bounds__(64) void k_h(const float* __restrict__ S,
                                          const float* __restrict__ SW1,
                                          const float* __restrict__ ws1,
                                          const float* __restrict__ K,
                                          const float* __restrict__ b1,
                                          const float* __restrict__ b2,
                                          const float* __restrict__ b3,
                                          const float* __restrict__ W3,
                                          float* __restrict__ H,
                                          float* __restrict__ v,
                                          float* __restrict__ w,
                                          float* __restrict__ T) {
    int c = blockIdx.x;
    int chunk = blockIdx.y;
    int lane = threadIdx.x;
    int n0 = chunk * 243;
    if (c < NCLS) {
        float acc[21];
        float av = 0.f, aw = 0.f;
#pragma unroll
        for (int t = 0; t < 21; ++t) acc[t] = 0.f;
        const float* w3row = W3 + (size_t)c * FUZZ;
        for (int n = n0 + lane; n < n0 + 243; n += 64) {
            float w3 = w3row[n];
            av += w3;
            aw += b2[n] * w3;
#pragma unroll
            for (int t = 0; t < 21; ++t)
                acc[t] += S[t * SSTR + n] * w3;
        }
        if (chunk < 8) {
            int i = chunk * 64 + lane;      // each lane exactly one i
            float kk = K[c * MID + i];
            av += ws1[i] * kk;
            aw += b1[i] * kk;
#pragma unroll
            for (int t = 0; t < 21; ++t)
                acc[t] += SW1[t * MID + i] * kk;
        }
#pragma unroll
        for (int t = 0; t < 21; ++t) acc[t] = wave_sum(acc[t]);
        av = wave_sum(av);
        aw = wave_sum(aw);
        if (lane == 0) {
#pragma unroll
            for (int t = 0; t < 21; ++t) atomicAdd(&H[t * NCLS + c], acc[t]);
            atomicAdd(&v[c], av);
            atomicAdd(&w[c], aw + (chunk == 0 ? b3[c] : 0.f));
        }
    } else {
        float acc[21];
#pragma unroll
        for (int t = 0; t < 21; ++t) acc[t] = 0.f;
        for (int n = n0 + lane; n < n0 + 243; n += 64) {
#pragma unroll
            for (int t = 0; t < 21; ++t) acc[t] += S[t * SSTR + n];
        }
#pragma unroll
        for (int t = 0; t < 21; ++t) acc[t] = wave_sum(acc[t]);
        if (lane == 0) {
#pragma unroll
            for (int t = 0; t < 21; ++t) atomicAdd(&T[t], acc[t]);
        }
    }
}

// ---------------------------------------------------------------------------
// Kernel 4: per-batch epilogue. 64 blocks x 64 threads spreads across CUs.
// ---------------------------------------------------------------------------
__global__ __launch_bounds__(64) void k_out(const float* __restrict__ x,
                                            const float* __restrict__ cc,
                                            const float* __restrict__ bbv,
                                            const float* __restrict__ bais,
                                            const float* __restrict__ T,
                                            const float* __restrict__ H,
                                            const float* __restrict__ v,
                                            const float* __restrict__ w,
                                            float* __restrict__ out) {
    int b = blockIdx.x * 64 + threadIdx.x;
    if (b >= BATCH) return;
    float xv[NFEAT];
#pragma unroll
    for (int j = 0; j < NFEAT; ++j) xv[j] = x[b * NFEAT + j];
    float u[21];
#pragma unroll
    for (int j = 0; j < NFEAT; ++j) {
#pragma unroll
        for (int m = 0; m < 3; ++m) {
            float d = xv[j] - cc[j * 3 + m];
            float bv = bbv[j * 3 + m];
            u[j * 3 + m] = expf(-(d * d) / (bv * bv));
        }
    }
    float ba = bais[0];
    float r = 2187.0f * ba;
#pragma unroll
    for (int t = 0; t < 21; ++t) r += u[t] * T[t];
    float inv = 1.0f / r;
#pragma unroll
    for (int c = 0; c < NCLS; ++c) {
        float s = 0.f;
#pragma unroll
        for (int t = 0; t < 21; ++t) s += u[t] * H[t * NCLS + c];
        float h = (s + ba * v[c]) * inv + w[c];
        out[b * NCLS + c] = (h >= 0.f) ? h : 0.2f * h;
    }
}

extern "C" void kernel_launch(void* const* d_in, const int* in_sizes, int n_in,
                              void* d_out, int out_size, void* d_ws, size_t ws_size,
                              hipStream_t stream) {
    const float* x    = (const float*)d_in[0];
    const float* c    = (const float*)d_in[1];
    const float* bbv  = (const float*)d_in[2];
    const float* wei  = (const float*)d_in[3];
    const float* bais = (const float*)d_in[4];
    const float* W1   = (const float*)d_in[5];
    const float* b1   = (const float*)d_in[6];
    const float* W2   = (const float*)d_in[7];
    const float* b2   = (const float*)d_in[8];
    const float* W3   = (const float*)d_in[9];
    const float* b3   = (const float*)d_in[10];

    // S, K, T/H/v/w contiguous so ONE memset zeroes everything atomics need.
    float* ws  = (float*)d_ws;
    float* S   = ws;                         // 21*SSTR           = 46032
    float* K   = S + 21 * SSTR;              // 10*512            = 5120
    float* T   = K + NCLS * MID;             // 32
    float* H   = T + 32;                     // 224 (21*10 used)
    float* v   = H + 224;                    // 16
    float* w   = v + 16;                     // 16   (T..w = 288)
    float* SW1 = w + 16;                     // 21*512
    float* ws1 = SW1 + 21 * MID;             // 512

    hipMemsetAsync(S, 0, (size_t)(21 * SSTR + NCLS * MID + 288) * sizeof(float),
                   stream);
    k_reduce_wei<<<dim3(9, 243), 256, 0, stream>>>(wei, S);
    k_sw1<<<MID + 270, 256, 0, stream>>>(S, W1, W2, W3, SW1, ws1, K);
    k_h<<<dim3(NCLS + 1, 9), 64, 0, stream>>>(S, SW1, ws1, K, b1, b2, b3, W3,
                                              H, v, w, T);
    k_out<<<(BATCH + 63) / 64, 64, 0, stream>>>(x, c, bbv, bais, T, H, v, w,
                                                (float*)d_out);
}